// Round 18
// baseline (1193.403 us; speedup 1.0000x reference)
//
#include <hip/hip_runtime.h>

#define NN 50000
#define BLK_E 4096   // edges per block in passes A/C (256 thr x 16)

typedef short bf16x8 __attribute__((ext_vector_type(8)));
typedef float f32x16 __attribute__((ext_vector_type(16)));

__device__ __forceinline__ unsigned bf16r(float f) {   // RNE round to bf16
    unsigned u = __float_as_uint(f);
    return (u + 0x7FFFu + ((u >> 16) & 1u)) >> 16;
}
__device__ __forceinline__ float bflo(unsigned u) { return __uint_as_float(u << 16); }
__device__ __forceinline__ float bfhi(unsigned u) { return __uint_as_float(u & 0xFFFF0000u); }

// Native LDS atomics via inline asm. Generic-pointer atomicAdd/unsafeAtomicAdd
// both lower to the flat/CAS path (~55cyc serialized each — R16/R17 both 584us,
// identical). ds_add_* is fire-and-forget: no return, no per-op wait. The
// 64->32 bit truncation IS the generic->AS3 cast on AMDGPU (2^32-aligned
// apertures). One lgkmcnt(0) drain before the phase barrier.
__device__ __forceinline__ void lds_fadd(float* p, float v) {
    asm volatile("ds_add_f32 %0, %1" :: "v"((uint)(uintptr_t)p), "v"(v));
}
__device__ __forceinline__ void lds_uadd(int* p, int v) {
    asm volatile("ds_add_u32 %0, %1" :: "v"((uint)(uintptr_t)p), "v"(v));
}

// ---------------- pass A: per-block dst>>8 histogram (+ W/x bf16 converts) ----

__global__ void passA_k(const int* __restrict__ ei, int E,
                        int* __restrict__ counts, int nebl,
                        const float* __restrict__ Wl, const float* __restrict__ Wr,
                        uint* __restrict__ wb,
                        const float* __restrict__ x, uint* __restrict__ xb, int nquad) {
    int bid = blockIdx.x;
    int t = threadIdx.x;
    if (bid < nebl) {
        __shared__ int dh[256];
        dh[t] = 0;
        __syncthreads();
        const int* dst = ei + E;
        int base = bid * BLK_E + t * 16;
        if (base + 16 <= E) {
            #pragma unroll
            for (int q = 0; q < 4; ++q) {
                int4 d4 = *(const int4*)(dst + base + q * 4);
                atomicAdd(&dh[d4.x >> 8], 1);
                atomicAdd(&dh[d4.y >> 8], 1);
                atomicAdd(&dh[d4.z >> 8], 1);
                atomicAdd(&dh[d4.w >> 8], 1);
            }
        } else {
            for (int e = base; e < E; ++e) atomicAdd(&dh[dst[e] >> 8], 1);
        }
        __syncthreads();
        counts[bid * 256 + t] = dh[t];
    } else if (bid < nebl + 64) {
        int i = (bid - nebl) * 256 + t;           // 0..16383
        int nrow = i >> 7;
        int k = (i & 127) * 2;
        const float* W = (k < 128) ? Wl : Wr;
        int kk = k & 127;
        uint lo = bf16r(W[nrow * 128 + kk]);
        uint hi = bf16r(W[nrow * 128 + kk + 1]);
        wb[i] = (hi << 16) | lo;
    } else {
        int i = (bid - nebl - 64) * 256 + t;
        if (i >= nquad) return;
        float4 v = ((const float4*)x)[i];
        uint2 p;
        p.x = (bf16r(v.y) << 16) | bf16r(v.x);
        p.y = (bf16r(v.w) << 16) | bf16r(v.z);
        ((uint2*)xb)[i] = p;
    }
}

// ---------------- pass B: column-exclusive prefix + bin bases ----------------

__global__ void passB_k(int* __restrict__ counts, int nebl,
                        int* __restrict__ binBase) {
    __shared__ int sm[256];
    int t = threadIdx.x;
    int run = 0;
    for (int b = 0; b < nebl; b += 8) {
        int v[8];
        #pragma unroll
        for (int j = 0; j < 8; ++j)
            v[j] = (b + j < nebl) ? counts[(b + j) * 256 + t] : 0;
        #pragma unroll
        for (int j = 0; j < 8; ++j) {
            if (b + j < nebl) counts[(b + j) * 256 + t] = run;
            run += v[j];
        }
    }
    int v = run;                      // column total
    sm[t] = v;
    __syncthreads();
    for (int off = 1; off < 256; off <<= 1) {
        int a = (t >= off) ? sm[t - off] : 0;
        __syncthreads();
        sm[t] += a;
        __syncthreads();
    }
    binBase[t] = sm[t] - v;           // exclusive
    if (t == 255) binBase[256] = sm[255];   // == E
}

// ---------------- pass C: scatter edges into dst>>8 partitions --------------
// upack = (dst&255)<<16 | src  (src < 50000 < 2^16)

__global__ void passC_k(const int* __restrict__ ei, int E,
                        const int* __restrict__ counts,
                        const int* __restrict__ binBase,
                        uint* __restrict__ upack, int nebl) {
    __shared__ int cur[256];
    int t = threadIdx.x, bid = blockIdx.x;
    cur[t] = counts[bid * 256 + t] + binBase[t];
    __syncthreads();
    const int* dst = ei + E;
    const int* src = ei;
    int base = bid * BLK_E + t * 16;
    if (base + 16 <= E) {
        #pragma unroll
        for (int q = 0; q < 4; ++q) {
            int4 d4 = *(const int4*)(dst + base + q * 4);
            int4 s4 = *(const int4*)(src + base + q * 4);
            int p;
            p = atomicAdd(&cur[d4.x >> 8], 1);
            upack[p] = ((uint)(d4.x & 255) << 16) | (uint)s4.x;
            p = atomicAdd(&cur[d4.y >> 8], 1);
            upack[p] = ((uint)(d4.y & 255) << 16) | (uint)s4.y;
            p = atomicAdd(&cur[d4.z >> 8], 1);
            upack[p] = ((uint)(d4.z & 255) << 16) | (uint)s4.z;
            p = atomicAdd(&cur[d4.w >> 8], 1);
            upack[p] = ((uint)(d4.w & 255) << 16) | (uint)s4.w;
        }
    } else {
        for (int e = base; e < E; ++e) {
            int d = dst[e];
            int p = atomicAdd(&cur[d >> 8], 1);
            upack[p] = ((uint)(d & 255) << 16) | (uint)src[e];
        }
    }
}

// ---------------- fused layer v2: edge-parallel LDS aggregation + MFMA -------
// Block = one 256-node partition, 1024 threads, acc[256][128] f32 in 128KB
// dynamic LDS. Sweep: 64 edge-slots x 16 col-lanes, all gathers independent;
// accumulate via native ds_add_f32 (asm). Bank-spread swizzle:
// phys granule p(g) = ((g>>1)^(ld&7)) | ((g&1)<<4).

#define ADD_EDGE(u, v)                                                        \
    {                                                                         \
        int ld_ = (int)((u) >> 16);                                           \
        int c_  = c16 ^ (ld_ & 7);                                            \
        float* r0_ = &acc[ld_ * 128 + (c_ << 2)];          /* granule 2c16  */ \
        float* r1_ = &acc[ld_ * 128 + ((16 + c_) << 2)];   /* granule 2c16+1*/ \
        lds_fadd(r0_ + 0, bflo((v).x));                                       \
        lds_fadd(r0_ + 1, bfhi((v).x));                                       \
        lds_fadd(r0_ + 2, bflo((v).y));                                       \
        lds_fadd(r0_ + 3, bfhi((v).y));                                       \
        lds_fadd(r1_ + 0, bflo((v).z));                                       \
        lds_fadd(r1_ + 1, bfhi((v).z));                                       \
        lds_fadd(r1_ + 2, bflo((v).w));                                       \
        lds_fadd(r1_ + 3, bfhi((v).w));                                       \
        if (c16 == 0) lds_uadd(&ideg[ld_], 1);                                \
    }

__global__ __launch_bounds__(1024) void fused_layer_k(
    const uint4* __restrict__ in4,    // bf16 rows [N][16 uint4]
    const int* __restrict__ binBase,  // [197] partition edge ranges
    const uint* __restrict__ upack,   // partition-sorted (local<<16)|src
    const ushort* __restrict__ Wb,    // [128][256] bf16
    const float* __restrict__ bl,
    float* __restrict__ out,          // f32 out or null
    ushort* __restrict__ hb,          // bf16 out or null
    int N, int relu) {
    extern __shared__ float acc[];            // [256][128] f32, swizzled
    int* ideg = (int*)(acc + 32768);          // [256]

    int tid = threadIdx.x;
    int p   = blockIdx.x;

    // zero acc + ideg (8192 + 64 uint4)
    uint4 z = {0, 0, 0, 0};
    uint4* az = (uint4*)acc;
    for (int i = tid; i < 8256; i += 1024) az[i] = z;
    __syncthreads();

    // ---- edge sweep: 64 edge-slots x 16 col-lanes, independent gathers ----
    int s0 = binBase[p], s1 = binBase[p + 1];
    int eg = tid >> 4, c16 = tid & 15;
    for (int e = s0 + eg; e < s1; e += 256) {
        int e1 = min(e + 64,  s1 - 1);
        int e2 = min(e + 128, s1 - 1);
        int e3 = min(e + 192, s1 - 1);
        uint u0 = upack[e],  u1 = upack[e1];
        uint u2 = upack[e2], u3 = upack[e3];
        uint4 r0 = in4[(size_t)(u0 & 0xFFFFu) * 16 + c16];
        uint4 r1 = in4[(size_t)(u1 & 0xFFFFu) * 16 + c16];
        uint4 r2 = in4[(size_t)(u2 & 0xFFFFu) * 16 + c16];
        uint4 r3 = in4[(size_t)(u3 & 0xFFFFu) * 16 + c16];
        ADD_EDGE(u0, r0);
        if (e + 64  < s1) ADD_EDGE(u1, r1);
        if (e + 128 < s1) ADD_EDGE(u2, r2);
        if (e + 192 < s1) ADD_EDGE(u3, r3);
    }
    // drain asm-issued DS ops (invisible to compiler's waitcnt tracking)
    asm volatile("s_waitcnt lgkmcnt(0)" ::: "memory");
    __syncthreads();

    // ---- MFMA phase: 16 waves = 8 m-tiles x 2 col-pairs ----
    int wid   = tid >> 6;
    int lane  = tid & 63;
    int mrow  = lane & 31;
    int khalf = lane >> 5;
    int mtile = wid >> 1;
    int ctb   = (wid & 1) * 2;
    int ld    = mtile * 32 + mrow;

    int dgv = ideg[ld];
    float inv = (dgv > 0) ? (1.f / (float)dgv) : 0.f;

    union { uint4 u; bf16x8 v; } cv;
    bf16x8 A[16];
    int key = ld & 7;
    #pragma unroll
    for (int ks = 0; ks < 8; ++ks) {
        int gb = ks * 4 + khalf * 2;          // even logical granule
        int p0 = (gb >> 1) ^ key;             // physical of gb
        int p1 = 16 + p0;                     // physical of gb+1
        float4 f0 = *(float4*)&acc[ld * 128 + p0 * 4];
        float4 f1 = *(float4*)&acc[ld * 128 + p1 * 4];
        cv.u.x = (bf16r(f0.y * inv) << 16) | bf16r(f0.x * inv);
        cv.u.y = (bf16r(f0.w * inv) << 16) | bf16r(f0.z * inv);
        cv.u.z = (bf16r(f1.y * inv) << 16) | bf16r(f1.x * inv);
        cv.u.w = (bf16r(f1.w * inv) << 16) | bf16r(f1.z * inv);
        A[ks] = cv.v;
    }
    int gm0 = p * 256 + ld;
    if (gm0 >= N) gm0 = N - 1;
    const ushort* ar1 = (const ushort*)in4 + (size_t)gm0 * 128 + khalf * 8;
    #pragma unroll
    for (int ks = 0; ks < 8; ++ks)
        A[8 + ks] = *reinterpret_cast<const bf16x8*>(ar1 + ks * 16);

    for (int ct = ctb; ct < ctb + 2; ++ct) {
        int nfeat = ct * 32 + mrow;
        bf16x8 B[16];
        const ushort* wrow = Wb + (size_t)nfeat * 256 + khalf * 8;
        #pragma unroll
        for (int ks = 0; ks < 16; ++ks)
            B[ks] = *reinterpret_cast<const bf16x8*>(wrow + ks * 16);

        f32x16 c = {};
        #pragma unroll
        for (int ks = 0; ks < 16; ++ks)
            c = __builtin_amdgcn_mfma_f32_32x32x16_bf16(A[ks], B[ks], c, 0, 0, 0);

        float bias = bl[nfeat];
        #pragma unroll
        for (int r2 = 0; r2 < 16; ++r2) {
            int rr = (r2 & 3) + 8 * (r2 >> 2) + 4 * khalf;
            int gm = p * 256 + mtile * 32 + rr;
            if (gm < N) {
                float vv = c[r2] + bias;
                if (relu) vv = fmaxf(vv, 0.f);
                if (out) out[(size_t)gm * 128 + nfeat] = vv;
                if (hb)  hb[(size_t)gm * 128 + nfeat] = (ushort)bf16r(vv);
            }
        }
    }
}

extern "C" void kernel_launch(void* const* d_in, const int* in_sizes, int n_in,
                              void* d_out, int out_size, void* d_ws, size_t ws_size,
                              hipStream_t stream) {
    const float* x  = (const float*)d_in[0];
    const int*   ei = (const int*)d_in[1];
    const float* Wl = (const float*)d_in[2];
    const float* bl = (const float*)d_in[3];
    const float* Wr = (const float*)d_in[4];
    float* out = (float*)d_out;

    const int N = NN;
    const int E = in_sizes[1] / 2;
    const int NPAD = 50016;

    int nebl = (E + BLK_E - 1) / BLK_E;       // 157
    int nprt = (N + 255) / 256;               // 196 partitions

    // ws layout (u32 units):
    // counts[nebl*256] | binBase[260] | upack[E] | wb[16384]
    // | xb[NPAD*64] | hb[NPAD*64]
    int*  ws      = (int*)d_ws;
    int*  counts  = ws;
    int*  binBase = counts + nebl * 256;
    uint* upack   = (uint*)(binBase + 260);
    uint* wb      = (uint*)(upack + E);
    uint* xb      = wb + 128 * 128;
    uint* hb      = xb + (size_t)NPAD * 64;

    int nquad = N * 32;
    int cvtb  = (nquad + 255) / 256;

    (void)hipFuncSetAttribute((const void*)fused_layer_k,
                              hipFuncAttributeMaxDynamicSharedMemorySize, 132096);

    passA_k<<<nebl + 64 + cvtb, 256, 0, stream>>>(ei, E, counts, nebl,
                                                  Wl, Wr, wb, x, xb, nquad);
    passB_k<<<1, 256, 0, stream>>>(counts, nebl, binBase);
    passC_k<<<nebl, 256, 0, stream>>>(ei, E, counts, binBase, upack, nebl);

    // layer 1: gather from xb, output bf16 hb only
    fused_layer_k<<<nprt, 1024, 132096, stream>>>((const uint4*)xb, binBase, upack,
                                                  (const ushort*)wb, bl,
                                                  (float*)nullptr, (ushort*)hb, N, 1);
    // layer 2: gather from hb, output f32 out
    fused_layer_k<<<nprt, 1024, 132096, stream>>>((const uint4*)hb, binBase, upack,
                                                  (const ushort*)wb, bl,
                                                  out, (ushort*)nullptr, N, 0);
}

// Round 19
// 139.606 us; speedup vs baseline: 8.5484x; 8.5484x over previous
//
#include <hip/hip_runtime.h>

#define NN 50000
#define D 128
#define BLK_E 4096   // edges per block in passes A/C (256 thr x 16)

typedef short bf16x8 __attribute__((ext_vector_type(8)));
typedef float f32x16 __attribute__((ext_vector_type(16)));

__device__ __forceinline__ unsigned bf16r(float f) {   // RNE round to bf16
    unsigned u = __float_as_uint(f);
    return (u + 0x7FFFu + ((u >> 16) & 1u)) >> 16;
}
__device__ __forceinline__ float bflo(unsigned u) { return __uint_as_float(u << 16); }
__device__ __forceinline__ float bfhi(unsigned u) { return __uint_as_float(u & 0xFFFF0000u); }

// ---------------- pass A: per-block dst>>8 histogram (+ W/x bf16 converts) ----

__global__ void passA_k(const int* __restrict__ ei, int E,
                        int* __restrict__ counts, int nebl,
                        const float* __restrict__ Wl, const float* __restrict__ Wr,
                        uint* __restrict__ wb,
                        const float* __restrict__ x, uint* __restrict__ xb, int nquad) {
    int bid = blockIdx.x;
    int t = threadIdx.x;
    if (bid < nebl) {
        __shared__ int dh[256];
        dh[t] = 0;
        __syncthreads();
        const int* dst = ei + E;
        int base = bid * BLK_E + t * 16;
        if (base + 16 <= E) {
            #pragma unroll
            for (int q = 0; q < 4; ++q) {
                int4 d4 = *(const int4*)(dst + base + q * 4);
                atomicAdd(&dh[d4.x >> 8], 1);
                atomicAdd(&dh[d4.y >> 8], 1);
                atomicAdd(&dh[d4.z >> 8], 1);
                atomicAdd(&dh[d4.w >> 8], 1);
            }
        } else {
            for (int e = base; e < E; ++e) atomicAdd(&dh[dst[e] >> 8], 1);
        }
        __syncthreads();
        counts[bid * 256 + t] = dh[t];
    } else if (bid < nebl + 64) {
        int i = (bid - nebl) * 256 + t;           // 0..16383
        int nrow = i >> 7;
        int k = (i & 127) * 2;
        const float* W = (k < 128) ? Wl : Wr;
        int kk = k & 127;
        uint lo = bf16r(W[nrow * 128 + kk]);
        uint hi = bf16r(W[nrow * 128 + kk + 1]);
        wb[i] = (hi << 16) | lo;
    } else {
        int i = (bid - nebl - 64) * 256 + t;
        if (i >= nquad) return;
        float4 v = ((const float4*)x)[i];
        uint2 p;
        p.x = (bf16r(v.y) << 16) | bf16r(v.x);
        p.y = (bf16r(v.w) << 16) | bf16r(v.z);
        ((uint2*)xb)[i] = p;
    }
}

// ---------------- pass B: column-exclusive prefix + bin bases ----------------

__global__ void passB_k(int* __restrict__ counts, int nebl,
                        int* __restrict__ binBase) {
    __shared__ int sm[256];
    int t = threadIdx.x;
    int run = 0;
    for (int b = 0; b < nebl; b += 8) {
        int v[8];
        #pragma unroll
        for (int j = 0; j < 8; ++j)
            v[j] = (b + j < nebl) ? counts[(b + j) * 256 + t] : 0;
        #pragma unroll
        for (int j = 0; j < 8; ++j) {
            if (b + j < nebl) counts[(b + j) * 256 + t] = run;
            run += v[j];
        }
    }
    int v = run;                      // column total
    sm[t] = v;
    __syncthreads();
    for (int off = 1; off < 256; off <<= 1) {
        int a = (t >= off) ? sm[t - off] : 0;
        __syncthreads();
        sm[t] += a;
        __syncthreads();
    }
    binBase[t] = sm[t] - v;           // exclusive
    if (t == 255) binBase[256] = sm[255];   // == E
}

// ---------------- pass C: scatter edges into dst>>8 partitions --------------
// upack = (dst&255)<<16 | src  (src < 50000 < 2^16)

__global__ void passC_k(const int* __restrict__ ei, int E,
                        const int* __restrict__ counts,
                        const int* __restrict__ binBase,
                        uint* __restrict__ upack, int nebl) {
    __shared__ int cur[256];
    int t = threadIdx.x, bid = blockIdx.x;
    cur[t] = counts[bid * 256 + t] + binBase[t];
    __syncthreads();
    const int* dst = ei + E;
    const int* src = ei;
    int base = bid * BLK_E + t * 16;
    if (base + 16 <= E) {
        #pragma unroll
        for (int q = 0; q < 4; ++q) {
            int4 d4 = *(const int4*)(dst + base + q * 4);
            int4 s4 = *(const int4*)(src + base + q * 4);
            int p;
            p = atomicAdd(&cur[d4.x >> 8], 1);
            upack[p] = ((uint)(d4.x & 255) << 16) | (uint)s4.x;
            p = atomicAdd(&cur[d4.y >> 8], 1);
            upack[p] = ((uint)(d4.y & 255) << 16) | (uint)s4.y;
            p = atomicAdd(&cur[d4.z >> 8], 1);
            upack[p] = ((uint)(d4.z & 255) << 16) | (uint)s4.z;
            p = atomicAdd(&cur[d4.w >> 8], 1);
            upack[p] = ((uint)(d4.w & 255) << 16) | (uint)s4.w;
        }
    } else {
        for (int e = base; e < E; ++e) {
            int d = dst[e];
            int p = atomicAdd(&cur[d >> 8], 1);
            upack[p] = ((uint)(d & 255) << 16) | (uint)src[e];
        }
    }
}

// ---------------- pass D: per-partition CSR build (LDS only) ----------------
// Block p owns dsts [p*256, p*256+256) and edge segment
// [binBase[p], binBase[p+1]). LDS hist -> LDS scan -> packed rowptr + csrW.

__global__ void passD_k(const uint* __restrict__ upack,
                        const int* __restrict__ binBase,
                        int* __restrict__ rowptr, ushort* __restrict__ csrW, int N) {
    __shared__ int lh[256], sm[256], cur[256];
    int p = blockIdx.x, t = threadIdx.x;
    int s0 = binBase[p], s1 = binBase[p + 1];
    lh[t] = 0;
    __syncthreads();
    for (int e = s0 + t; e < s1; e += 256)
        atomicAdd(&lh[upack[e] >> 16], 1);
    __syncthreads();
    int v = lh[t];
    sm[t] = v;
    __syncthreads();
    for (int off = 1; off < 256; off <<= 1) {
        int a = (t >= off) ? sm[t - off] : 0;
        __syncthreads();
        sm[t] += a;
        __syncthreads();
    }
    int lbase = sm[t] - v;            // exclusive within partition
    int d = p * 256 + t;
    if (d <= N) rowptr[d] = s0 + lbase;   // d==N writes rowptr[N]=E (p=195,t=80)
    cur[t] = lbase;
    __syncthreads();
    for (int e = s0 + t; e < s1; e += 256) {
        uint u = upack[e];
        int r = atomicAdd(&cur[u >> 16], 1);
        csrW[s0 + r] = (ushort)(u & 0xFFFFu);
    }
}

// ---------------- fused layer: agg(32 nodes) -> LDS -> MFMA ----------
// 256 thr = 16 nodes x 16 uint4-cols, 2 sequential node-groups, 4-deep batch.
// This structure is the measured optimum across R6-R18: the gather phase is
// FETCH-bound (~88MB L2-miss traffic from the 8-XCD duplication of the 12.8MB
// image, served at ~2TB/s) — deeper chains (R9/R10/R15), CSR encodings
// (R12-R14), and edge-parallel LDS atomics (R16-R18, 3.4cyc/lane-op HW limit)
// all failed to beat it.

#define ACC8(v)                                                         \
    s0 += bflo(v.x); s1 += bfhi(v.x); s2 += bflo(v.y); s3 += bfhi(v.y); \
    s4 += bflo(v.z); s5 += bfhi(v.z); s6 += bflo(v.w); s7 += bfhi(v.w);

__global__ __launch_bounds__(256) void fused_layer_k(
    const uint4* __restrict__ in4,    // bf16 rows [N][16 uint4]
    const int* __restrict__ rowptr,   // [N+1] packed
    const ushort* __restrict__ csrW,  // [E] packed neighbor srcs
    const ushort* __restrict__ Wb,    // [128][256] bf16
    const float* __restrict__ bl,
    float* __restrict__ out,          // f32 out or null
    ushort* __restrict__ hb,          // bf16 out or null
    int N, int relu) {
    __shared__ uint4 At[32][16];

    int tid = threadIdx.x;
    int mt  = blockIdx.x;

    // ---- phase 1: aggregate (2 groups of 16 nodes) ----
    int lnode = tid >> 4;
    int c16   = tid & 15;
    #pragma unroll
    for (int g = 0; g < 2; ++g) {
        int lrow = g * 16 + lnode;
        int n = mt * 32 + lrow;
        float s0=0,s1=0,s2=0,s3=0,s4=0,s5=0,s6=0,s7=0;
        float inv = 0.f;
        if (n < N) {
            int ro  = rowptr[n];
            int deg = rowptr[n + 1] - ro;
            int i = 0;
            for (; i + 4 <= deg; i += 4) {
                int e0 = csrW[ro+i+0], e1 = csrW[ro+i+1];
                int e2 = csrW[ro+i+2], e3 = csrW[ro+i+3];
                uint4 v0 = in4[(size_t)e0 * 16 + c16];
                uint4 v1 = in4[(size_t)e1 * 16 + c16];
                uint4 v2 = in4[(size_t)e2 * 16 + c16];
                uint4 v3 = in4[(size_t)e3 * 16 + c16];
                ACC8(v0); ACC8(v1); ACC8(v2); ACC8(v3);
            }
            for (; i + 2 <= deg; i += 2) {
                int e0 = csrW[ro + i], e1 = csrW[ro + i + 1];
                uint4 v0 = in4[(size_t)e0 * 16 + c16];
                uint4 v1 = in4[(size_t)e1 * 16 + c16];
                ACC8(v0); ACC8(v1);
            }
            if (i < deg) {
                uint4 v0 = in4[(size_t)csrW[ro + i] * 16 + c16];
                ACC8(v0);
            }
            inv = (deg > 0) ? (1.f / (float)deg) : 0.f;
        }
        uint4 r;
        r.x = (bf16r(s1 * inv) << 16) | bf16r(s0 * inv);
        r.y = (bf16r(s3 * inv) << 16) | bf16r(s2 * inv);
        r.z = (bf16r(s5 * inv) << 16) | bf16r(s4 * inv);
        r.w = (bf16r(s7 * inv) << 16) | bf16r(s6 * inv);
        At[lrow][c16 ^ (lrow & 7)] = r;
    }
    __syncthreads();

    // ---- phase 2: MFMA ----
    int wid   = tid >> 6;
    int lane  = tid & 63;
    int col   = lane & 31;
    int khalf = lane >> 5;
    int nfeat = wid * 32 + col;

    bf16x8 B[16], A[16];
    const ushort* wrow = Wb + (size_t)nfeat * 256 + khalf * 8;
    #pragma unroll
    for (int ks = 0; ks < 16; ++ks)
        B[ks] = *reinterpret_cast<const bf16x8*>(wrow + ks * 16);

    #pragma unroll
    for (int ks = 0; ks < 8; ++ks) {
        int cc = (ks * 2 + khalf) ^ (col & 7);
        A[ks] = *reinterpret_cast<const bf16x8*>(&At[col][cc]);
    }
    int rowc = min(mt * 32 + col, N - 1);
    const ushort* ar1 = (const ushort*)in4 + (size_t)rowc * 128 + khalf * 8;
    #pragma unroll
    for (int ks = 0; ks < 8; ++ks)
        A[8 + ks] = *reinterpret_cast<const bf16x8*>(ar1 + ks * 16);

    f32x16 acc = {};
    #pragma unroll
    for (int ks = 0; ks < 16; ++ks)
        acc = __builtin_amdgcn_mfma_f32_32x32x16_bf16(A[ks], B[ks], acc, 0, 0, 0);

    float bias = bl[nfeat];
    #pragma unroll
    for (int r2 = 0; r2 < 16; ++r2) {
        int rr = (r2 & 3) + 8 * (r2 >> 2) + 4 * khalf;
        int gm = mt * 32 + rr;
        if (gm < N) {
            float v = acc[r2] + bias;
            if (relu) v = fmaxf(v, 0.f);
            if (out) __builtin_nontemporal_store(v, out + (size_t)gm * 128 + nfeat);
            if (hb)  hb[(size_t)gm * 128 + nfeat] = (ushort)bf16r(v);
        }
    }
}

extern "C" void kernel_launch(void* const* d_in, const int* in_sizes, int n_in,
                              void* d_out, int out_size, void* d_ws, size_t ws_size,
                              hipStream_t stream) {
    const float* x  = (const float*)d_in[0];
    const int*   ei = (const int*)d_in[1];
    const float* Wl = (const float*)d_in[2];
    const float* bl = (const float*)d_in[3];
    const float* Wr = (const float*)d_in[4];
    float* out = (float*)d_out;

    const int N = NN;
    const int E = in_sizes[1] / 2;
    const int NPAD = 50016;

    int nebl = (E + BLK_E - 1) / BLK_E;       // 157

    // ws layout (u32 units):
    // rowptr[50016] | counts[nebl*256] | binBase[260] | upack[E]
    // | csrW ushort[E] (E/2 u32) | wb[16384] | xb[NPAD*64] | hb[NPAD*64]
    int*    ws      = (int*)d_ws;
    int*    rowptr  = ws;
    int*    counts  = ws + 50016;
    int*    binBase = counts + nebl * 256;
    uint*   upack   = (uint*)(binBase + 260);
    ushort* csrW    = (ushort*)(upack + E);
    uint*   wb      = (uint*)(csrW + E);      // E even -> 4B aligned
    uint*   xb      = wb + 128 * 128;
    uint*   hb      = xb + (size_t)NPAD * 64;

    int nquad = N * 32;
    int cvtb  = (nquad + 255) / 256;

    passA_k<<<nebl + 64 + cvtb, 256, 0, stream>>>(ei, E, counts, nebl,
                                                  Wl, Wr, wb, x, xb, nquad);
    passB_k<<<1, 256, 0, stream>>>(counts, nebl, binBase);
    passC_k<<<nebl, 256, 0, stream>>>(ei, E, counts, binBase, upack, nebl);
    passD_k<<<(N + 256) / 256, 256, 0, stream>>>(upack, binBase, rowptr, csrW, N);

    int mtiles = (N + 31) / 32;        // 1563
    // layer 1: gather from xb, output bf16 hb only
    fused_layer_k<<<mtiles, 256, 0, stream>>>((const uint4*)xb, rowptr, csrW,
                                              (const ushort*)wb, bl,
                                              (float*)nullptr, (ushort*)hb, N, 1);
    // layer 2: gather from hb, output f32 out (nontemporal)
    fused_layer_k<<<mtiles, 256, 0, stream>>>((const uint4*)hb, rowptr, csrW,
                                              (const ushort*)wb, bl,
                                              out, (ushort*)nullptr, N, 0);
}